// Round 6
// baseline (280.113 us; speedup 1.0000x reference)
//
#include <hip/hip_runtime.h>
#include <hip/hip_bf16.h>

// BertSelfAttention (no mask). B=4, S=2048, H=1024, NH=16, HD=64. fp32 I/O.
// Round 5: attn LDS trimmed to 48 KB (3 blocks/CU) via swizzled P slab;
// qkv swapped-operand MFMA for Q/K -> vector epilogue; fused conv kernel.
#define BB  4
#define SS  2048
#define HH  1024
#define NHH 16
#define HDD 64

typedef unsigned short u16;
typedef unsigned int   u32;
using bf16x8 = __attribute__((ext_vector_type(8))) short;   // 8 bf16 = 4 VGPRs
using f32x4  = __attribute__((ext_vector_type(4))) float;   // MFMA C/D

// fp32 -> bf16 RNE.
__device__ __forceinline__ u16 f2b(float f) {
    union { float f; u32 u; } x; x.f = f;
    return (u16)((x.u + 0x7fffu + ((x.u >> 16) & 1u)) >> 16);
}
// fp32 -> bf16 round-half-up (positive values; 0.5-ulp worst case).
__device__ __forceinline__ u16 f2b_fast(float f) {
    union { float f; u32 u; } x; x.f = f;
    return (u16)((x.u + 0x8000u) >> 16);
}

// async 16B global -> LDS (dest = wave-uniform base + lane*16).
__device__ __forceinline__ void gload16(const u16* g, u16* l) {
    __builtin_amdgcn_global_load_lds(
        (const __attribute__((address_space(1))) void*)g,
        (__attribute__((address_space(3))) void*)l, 16, 0, 0);
}

// ---------------------------------------------------------------------------
// conv: fused input conversion.
//   blocks [0,4096):      X fp32 -> bf16 straight copy (8 elems/thread)
//   blocks [4096,7168):   W[k][n] fp32 -> Wt[n][k] bf16 (32x32 transpose)
// ---------------------------------------------------------------------------
__global__ __launch_bounds__(256) void conv(
    const float* __restrict__ X,
    const float* __restrict__ Wq, const float* __restrict__ Wk,
    const float* __restrict__ Wv,
    u16* __restrict__ Xb, u16* __restrict__ Wt)
{
    const int bid = blockIdx.x;
    const int t = threadIdx.x;
    if (bid < 4096) {
        const int i = bid * 256 + t;
        float4 a = ((const float4*)X)[i * 2];
        float4 b = ((const float4*)X)[i * 2 + 1];
        ushort4 s0, s1;
        s0.x = f2b(a.x); s0.y = f2b(a.y); s0.z = f2b(a.z); s0.w = f2b(a.w);
        s1.x = f2b(b.x); s1.y = f2b(b.y); s1.z = f2b(b.z); s1.w = f2b(b.w);
        ((ushort4*)Xb)[i * 2] = s0;
        ((ushort4*)Xb)[i * 2 + 1] = s1;
        return;
    }
    const int idx = bid - 4096;
    const int z = idx >> 10, rem = idx & 1023;
    const int k0 = (rem >> 5) * 32, n0 = (rem & 31) * 32;
    const float* W = (z == 0) ? Wq : (z == 1) ? Wk : Wv;
    u16* out = Wt + (size_t)z * HH * HH;
    __shared__ float T[32][33];
    {
        const int kl = t >> 3, n4 = (t & 7) * 4;
        float4 v = *(const float4*)&W[(size_t)(k0 + kl) * HH + n0 + n4];
        T[n4 + 0][kl] = v.x; T[n4 + 1][kl] = v.y;
        T[n4 + 2][kl] = v.z; T[n4 + 3][kl] = v.w;
    }
    __syncthreads();
    {
        const int nl = t >> 3, k4 = (t & 7) * 4;
        ushort4 s;
        s.x = f2b(T[nl][k4 + 0]); s.y = f2b(T[nl][k4 + 1]);
        s.z = f2b(T[nl][k4 + 2]); s.w = f2b(T[nl][k4 + 3]);
        *(ushort4*)&out[(size_t)(n0 + nl) * HH + k0 + k4] = s;
    }
}

// ---------------------------------------------------------------------------
// qkv_gemm: 128x128 tile, BK=64, global_load_lds + XOR swizzle, 4 waves 2x2.
// z<2 (Q,K): operands SWAPPED -> acc = D^T (regs step d) -> ushort4 stores
//            into [b,h,s,d]. Q pre-scaled by 0.125*log2(e).
// z=2 (V):   normal order (regs step s) -> ushort4 stores into V^T [b,h,d,s].
// ---------------------------------------------------------------------------
__global__ __launch_bounds__(256) void qkv_gemm(
    const u16* __restrict__ Xb, const u16* __restrict__ Wtb,
    const float* __restrict__ bq, const float* __restrict__ bk,
    const float* __restrict__ bv,
    u16* __restrict__ Qw, u16* __restrict__ Kw, u16* __restrict__ Vw)
{
    const int z  = blockIdx.z;
    const float* bias = (z == 0) ? bq : (z == 1) ? bk : bv;
    const int m0 = blockIdx.x * 128, n0 = blockIdx.y * 128;

    __shared__ __align__(16) u16 Xs[128 * 64];
    __shared__ __align__(16) u16 Ws[128 * 64];

    const int t = threadIdx.x;
    const int w = t >> 6, lane = t & 63, lr = lane & 15, quad = lane >> 4;
    const int l3 = lane >> 3, c7 = lane & 7;
    const int cl = (c7 ^ l3) * 8;          // swizzled source column (u16)
    const int wm = w >> 1, wn = w & 1;

    const u16* Wtz = Wtb + (size_t)z * HH * HH;

    f32x4 acc[4][4];
    #pragma unroll
    for (int i = 0; i < 4; i++)
        #pragma unroll
        for (int j = 0; j < 4; j++) acc[i][j] = f32x4{0.f, 0.f, 0.f, 0.f};

    for (int k0 = 0; k0 < HH; k0 += 64) {
        #pragma unroll
        for (int e = 0; e < 4; e++) {
            const int r = w * 32 + e * 8 + l3;
            gload16(&Xb [(size_t)(m0 + r) * HH + k0 + cl], &Xs[(w * 32 + e * 8) * 64]);
            gload16(&Wtz[(size_t)(n0 + r) * HH + k0 + cl], &Ws[(w * 32 + e * 8) * 64]);
        }
        __syncthreads();

        #pragma unroll
        for (int kc = 0; kc < 2; kc++) {
            bf16x8 af[4], bfr[4];
            const int ph = ((kc * 4 + quad) ^ c7) * 8;
            #pragma unroll
            for (int mi = 0; mi < 4; mi++)
                af[mi] = *(const bf16x8*)&Xs[(wm * 64 + mi * 16 + lr) * 64 + ph];
            #pragma unroll
            for (int ni = 0; ni < 4; ni++)
                bfr[ni] = *(const bf16x8*)&Ws[(wn * 64 + ni * 16 + lr) * 64 + ph];
            if (z != 2) {   // swapped: acc[mi][ni] = (W.X^T) tile = D^T
                #pragma unroll
                for (int mi = 0; mi < 4; mi++)
                    #pragma unroll
                    for (int ni = 0; ni < 4; ni++)
                        acc[mi][ni] = __builtin_amdgcn_mfma_f32_16x16x32_bf16(
                            bfr[ni], af[mi], acc[mi][ni], 0, 0, 0);
            } else {
                #pragma unroll
                for (int mi = 0; mi < 4; mi++)
                    #pragma unroll
                    for (int ni = 0; ni < 4; ni++)
                        acc[mi][ni] = __builtin_amdgcn_mfma_f32_16x16x32_bf16(
                            af[mi], bfr[ni], acc[mi][ni], 0, 0, 0);
            }
        }
        __syncthreads();
    }

    if (z != 2) {
        // acc = D^T: col(lane&15) = s-row, reg r = d-direction.
        u16* dst = (z == 0) ? Qw : Kw;
        const float cs = (z == 0) ? 0.18033688011112042f : 1.0f;
        #pragma unroll
        for (int mi = 0; mi < 4; mi++) {
            const int sg = m0 + wm * 64 + mi * 16 + lr;
            const int b = sg >> 11, s = sg & 2047;
            #pragma unroll
            for (int ni = 0; ni < 4; ni++) {
                const int nb = n0 + wn * 64 + ni * 16 + quad * 4;
                const int h = nb >> 6, d0 = nb & 63;
                float4 bb4 = *(const float4*)&bias[nb];
                ushort4 vs;
                vs.x = f2b((acc[mi][ni][0] + bb4.x) * cs);
                vs.y = f2b((acc[mi][ni][1] + bb4.y) * cs);
                vs.z = f2b((acc[mi][ni][2] + bb4.z) * cs);
                vs.w = f2b((acc[mi][ni][3] + bb4.w) * cs);
                *(ushort4*)&dst[((size_t)(b * NHH + h) * SS + s) * HDD + d0] = vs;
            }
        }
    } else {
        // acc = D: col = d (n), reg r = s-direction -> V^T [b,h,d,s] stores.
        #pragma unroll
        for (int mi = 0; mi < 4; mi++)
            #pragma unroll
            for (int ni = 0; ni < 4; ni++) {
                const int mb = m0 + wm * 64 + mi * 16 + quad * 4;
                const int b = mb >> 11, s0 = mb & 2047;
                const int n = n0 + wn * 64 + ni * 16 + lr;
                const int h = n >> 6, d = n & 63;
                const float bv4 = bias[n];
                ushort4 vs;
                vs.x = f2b(acc[mi][ni][0] + bv4);
                vs.y = f2b(acc[mi][ni][1] + bv4);
                vs.z = f2b(acc[mi][ni][2] + bv4);
                vs.w = f2b(acc[mi][ni][3] + bv4);
                *(ushort4*)&Vw[((size_t)(b * NHH + h) * HDD + d) * SS + s0] = vs;
            }
    }
}

// ---------------------------------------------------------------------------
// attn: flash attention, M=0 softmax (p = exp2(s), Q pre-scaled), 512 threads
// = 8 waves, 128 q-rows/block. Double-buffered async K/V staging; P slab
// XOR-swizzled (no pad) -> total LDS 48.0 KB -> 3 blocks/CU (24 waves).
// ---------------------------------------------------------------------------
__global__ __launch_bounds__(512) void attn(
    const u16* __restrict__ Qb, const u16* __restrict__ Kb,
    const u16* __restrict__ Vtb, float* __restrict__ Out)
{
    // hh = bid&63: all 16 q-blocks of a head land on XCD (hh&7).
    const int bid = blockIdx.x;
    const int hh = bid & 63, qt = bid >> 6;      // qt 0..15
    const int b = hh >> 4, h = hh & 15;
    const size_t hb = (size_t)hh * SS * HDD;

    __shared__ __align__(16) u16 Ks[2][64 * 64];
    __shared__ __align__(16) u16 Vs[2][64 * 64];
    __shared__ __align__(16) u16 Ps[8][16 * 64];   // swizzled, no pad

    const int t = threadIdx.x;
    const int w = t >> 6, lane = t & 63, lr = lane & 15, quad = lane >> 4;
    const int l3 = lane >> 3, c7 = lane & 7;
    const int cl = (c7 ^ l3) * 8;          // swizzled source column (u16)

    // Q A-frags (A: m = lane&15, k = quad*8+j), kept in VGPRs.
    bf16x8 qa[2];
    #pragma unroll
    for (int kc = 0; kc < 2; kc++)
        qa[kc] = *(const bf16x8*)&Qb[hb + (size_t)(qt * 128 + w * 16 + lr) * HDD
                                     + kc * 32 + quad * 8];

    // preload tile 0 into buffer 0: wave w stages rows w*8..w*8+7 of K and V^T
    {
        const int r8 = w * 8 + l3;
        gload16(&Kb [hb + (size_t)r8 * HDD + cl], &Ks[0][w * 8 * 64]);
        gload16(&Vtb[hb + (size_t)r8 * SS + cl],  &Vs[0][w * 8 * 64]);
    }
    __syncthreads();

    float lsum[4] = {0.f, 0.f, 0.f, 0.f};
    f32x4 oc[4];
    #pragma unroll
    for (int ni = 0; ni < 4; ni++) oc[ni] = f32x4{0.f, 0.f, 0.f, 0.f};

    for (int kt = 0; kt < SS / 64; kt++) {
        const int bb = kt & 1;
        if (kt + 1 < SS / 64) {   // prefetch next tile into the other buffer
            const int r8 = w * 8 + l3;
            gload16(&Kb [hb + (size_t)((kt + 1) * 64 + r8) * HDD + cl],
                    &Ks[bb ^ 1][w * 8 * 64]);
            gload16(&Vtb[hb + (size_t)r8 * SS + (kt + 1) * 64 + cl],
                    &Vs[bb ^ 1][w * 8 * 64]);
        }

        // ---- S = Q K^T (scores already include 1/8*log2e via Q)
        f32x4 sc4[4];
        #pragma unroll
        for (int ni = 0; ni < 4; ni++) sc4[ni] = f32x4{0.f, 0.f, 0.f, 0.f};
        #pragma unroll
        for (int kc = 0; kc < 2; kc++) {
            const int ph = ((kc * 4 + quad) ^ c7) * 8;
            #pragma unroll
            for (int ni = 0; ni < 4; ni++) {
                bf16x8 kf = *(const bf16x8*)&Ks[bb][(ni * 16 + lr) * 64 + ph];
                sc4[ni] = __builtin_amdgcn_mfma_f32_16x16x32_bf16(qa[kc], kf, sc4[ni], 0, 0, 0);
            }
        }

        // ---- p = exp2(s); per-lane row sums; pack to swizzled P slab.
        //      logical (row = quad*4+r, col = ni*16+lr); chunk-XOR by row&7.
        #pragma unroll
        for (int ni = 0; ni < 4; ni++)
            #pragma unroll
            for (int r = 0; r < 4; r++) {
                const float pv = __builtin_amdgcn_exp2f(sc4[ni][r]);
                lsum[r] += pv;
                const int row = quad * 4 + r;
                const int pc = ((ni * 2 + (lr >> 3)) ^ (row & 7)) * 8 + (lr & 7);
                Ps[w][row * 64 + pc] = f2b_fast(pv);
            }

        // ---- P: C-layout -> A-layout (row = lr, chunks kc*4+quad, XOR lr&7)
        bf16x8 pa[2];
        #pragma unroll
        for (int kc = 0; kc < 2; kc++)
            pa[kc] = *(const bf16x8*)&Ps[w][lr * 64 + (((kc * 4 + quad) ^ (lr & 7)) * 8)];

        // ---- O += P V
        #pragma unroll
        for (int kc = 0; kc < 2; kc++) {
            const int ph = ((kc * 4 + quad) ^ c7) * 8;
            #pragma unroll
            for (int ni = 0; ni < 4; ni++) {
                bf16x8 vf = *(const bf16x8*)&Vs[bb][(ni * 16 + lr) * 64 + ph];
                oc[ni] = __builtin_amdgcn_mfma_f32_16x16x32_bf16(pa[kc], vf, oc[ni], 0, 0, 0);
            }
        }
        __syncthreads();   // reads of buf bb done; prefetch into bb^1 landed
    }

    // one-time l reduction across the 16 lanes sharing each row group
    #pragma unroll
    for (int off = 1; off < 16; off <<= 1)
        #pragma unroll
        for (int r = 0; r < 4; r++)
            lsum[r] += __shfl_xor(lsum[r], off);

    float inv[4];
    #pragma unroll
    for (int r = 0; r < 4; r++) inv[r] = 1.0f / lsum[r];
    #pragma unroll
    for (int ni = 0; ni < 4; ni++)
        #pragma unroll
        for (int r = 0; r < 4; r++) {
            const int rq = qt * 128 + w * 16 + quad * 4 + r;
            Out[((size_t)(b * SS + rq)) * HH + h * HDD + ni * 16 + lr] =
                oc[ni][r] * inv[r];
        }
}

// ---------------------------------------------------------------------------
extern "C" void kernel_launch(void* const* d_in, const int* in_sizes, int n_in,
                              void* d_out, int out_size, void* d_ws, size_t ws_size,
                              hipStream_t stream) {
    const float* X  = (const float*)d_in[0];
    const float* Wq = (const float*)d_in[1];
    const float* bq = (const float*)d_in[2];
    const float* Wk = (const float*)d_in[3];
    const float* bk = (const float*)d_in[4];
    const float* Wv = (const float*)d_in[5];
    const float* bv = (const float*)d_in[6];
    float* Out = (float*)d_out;

    const size_t elems = (size_t)BB * SS * HH;  // 8,388,608
    u16* Qw = (u16*)d_ws;                        // Q (pre-scaled) [b,h,s,d]
    u16* Kw = Qw + elems;                        // K [b,h,s,d]
    u16* Vw = Kw + elems;                        // V^T [b,h,d,s]
    // Xb/Wt scratch in d_out (23.1 MB < 33.5 MB; attn fully overwrites).
    u16* Xb = (u16*)d_out;
    u16* Wt = Xb + elems;

    conv<<<dim3(4096 + 3072), 256, 0, stream>>>(X, Wq, Wk, Wv, Xb, Wt);
    qkv_gemm<<<dim3(64, 8, 3), 256, 0, stream>>>(Xb, Wt, bq, bk, bv, Qw, Kw, Vw);
    attn<<<dim3(1024), 512, 0, stream>>>(Qw, Kw, Vw, Out);
}

// Round 7
// 255.655 us; speedup vs baseline: 1.0957x; 1.0957x over previous
//
#include <hip/hip_runtime.h>
#include <hip/hip_bf16.h>

// BertSelfAttention (no mask). B=4, S=2048, H=1024, NH=16, HD=64. fp32 I/O.
// Round 6: attn computes S^T (swapped-operand QK MFMA) so the P pack is
// in-lane contiguous: v_perm pair-pack + ds_write_b64, scalar lsum.
#define BB  4
#define SS  2048
#define HH  1024
#define NHH 16
#define HDD 64

typedef unsigned short u16;
typedef unsigned int   u32;
using bf16x8 = __attribute__((ext_vector_type(8))) short;   // 8 bf16 = 4 VGPRs
using f32x4  = __attribute__((ext_vector_type(4))) float;   // MFMA C/D

// fp32 -> bf16 RNE.
__device__ __forceinline__ u16 f2b(float f) {
    union { float f; u32 u; } x; x.f = f;
    return (u16)((x.u + 0x7fffu + ((x.u >> 16) & 1u)) >> 16);
}
// pack two positive fp32 -> bf16x2 in a u32 (round-half-up, 0.5 ulp).
__device__ __forceinline__ u32 pk2b(float lo, float hi) {
    union { float f; u32 u; } a, b; a.f = lo; b.f = hi;
    return __builtin_amdgcn_perm(b.u + 0x8000u, a.u + 0x8000u, 0x07060302u);
}

// async 16B global -> LDS (dest = wave-uniform base + lane*16).
__device__ __forceinline__ void gload16(const u16* g, u16* l) {
    __builtin_amdgcn_global_load_lds(
        (const __attribute__((address_space(1))) void*)g,
        (__attribute__((address_space(3))) void*)l, 16, 0, 0);
}

// ---------------------------------------------------------------------------
// conv: fused input conversion.
//   blocks [0,4096):      X fp32 -> bf16 straight copy (8 elems/thread)
//   blocks [4096,7168):   W[k][n] fp32 -> Wt[n][k] bf16 (32x32 transpose)
// ---------------------------------------------------------------------------
__global__ __launch_bounds__(256) void conv(
    const float* __restrict__ X,
    const float* __restrict__ Wq, const float* __restrict__ Wk,
    const float* __restrict__ Wv,
    u16* __restrict__ Xb, u16* __restrict__ Wt)
{
    const int bid = blockIdx.x;
    const int t = threadIdx.x;
    if (bid < 4096) {
        const int i = bid * 256 + t;
        float4 a = ((const float4*)X)[i * 2];
        float4 b = ((const float4*)X)[i * 2 + 1];
        ushort4 s0, s1;
        s0.x = f2b(a.x); s0.y = f2b(a.y); s0.z = f2b(a.z); s0.w = f2b(a.w);
        s1.x = f2b(b.x); s1.y = f2b(b.y); s1.z = f2b(b.z); s1.w = f2b(b.w);
        ((ushort4*)Xb)[i * 2] = s0;
        ((ushort4*)Xb)[i * 2 + 1] = s1;
        return;
    }
    const int idx = bid - 4096;
    const int z = idx >> 10, rem = idx & 1023;
    const int k0 = (rem >> 5) * 32, n0 = (rem & 31) * 32;
    const float* W = (z == 0) ? Wq : (z == 1) ? Wk : Wv;
    u16* out = Wt + (size_t)z * HH * HH;
    __shared__ float T[32][33];
    {
        const int kl = t >> 3, n4 = (t & 7) * 4;
        float4 v = *(const float4*)&W[(size_t)(k0 + kl) * HH + n0 + n4];
        T[n4 + 0][kl] = v.x; T[n4 + 1][kl] = v.y;
        T[n4 + 2][kl] = v.z; T[n4 + 3][kl] = v.w;
    }
    __syncthreads();
    {
        const int nl = t >> 3, k4 = (t & 7) * 4;
        ushort4 s;
        s.x = f2b(T[nl][k4 + 0]); s.y = f2b(T[nl][k4 + 1]);
        s.z = f2b(T[nl][k4 + 2]); s.w = f2b(T[nl][k4 + 3]);
        *(ushort4*)&out[(size_t)(n0 + nl) * HH + k0 + k4] = s;
    }
}

// ---------------------------------------------------------------------------
// qkv_gemm: 128x128 tile, BK=64, global_load_lds + XOR swizzle, 4 waves 2x2.
// z<2 (Q,K): operands SWAPPED -> acc = D^T (regs step d) -> ushort4 stores
//            into [b,h,s,d]. Q pre-scaled by 0.125*log2(e).
// z=2 (V):   normal order (regs step s) -> ushort4 stores into V^T [b,h,d,s].
// ---------------------------------------------------------------------------
__global__ __launch_bounds__(256) void qkv_gemm(
    const u16* __restrict__ Xb, const u16* __restrict__ Wtb,
    const float* __restrict__ bq, const float* __restrict__ bk,
    const float* __restrict__ bv,
    u16* __restrict__ Qw, u16* __restrict__ Kw, u16* __restrict__ Vw)
{
    const int z  = blockIdx.z;
    const float* bias = (z == 0) ? bq : (z == 1) ? bk : bv;
    const int m0 = blockIdx.x * 128, n0 = blockIdx.y * 128;

    __shared__ __align__(16) u16 Xs[128 * 64];
    __shared__ __align__(16) u16 Ws[128 * 64];

    const int t = threadIdx.x;
    const int w = t >> 6, lane = t & 63, lr = lane & 15, quad = lane >> 4;
    const int l3 = lane >> 3, c7 = lane & 7;
    const int cl = (c7 ^ l3) * 8;          // swizzled source column (u16)
    const int wm = w >> 1, wn = w & 1;

    const u16* Wtz = Wtb + (size_t)z * HH * HH;

    f32x4 acc[4][4];
    #pragma unroll
    for (int i = 0; i < 4; i++)
        #pragma unroll
        for (int j = 0; j < 4; j++) acc[i][j] = f32x4{0.f, 0.f, 0.f, 0.f};

    for (int k0 = 0; k0 < HH; k0 += 64) {
        #pragma unroll
        for (int e = 0; e < 4; e++) {
            const int r = w * 32 + e * 8 + l3;
            gload16(&Xb [(size_t)(m0 + r) * HH + k0 + cl], &Xs[(w * 32 + e * 8) * 64]);
            gload16(&Wtz[(size_t)(n0 + r) * HH + k0 + cl], &Ws[(w * 32 + e * 8) * 64]);
        }
        __syncthreads();

        #pragma unroll
        for (int kc = 0; kc < 2; kc++) {
            bf16x8 af[4], bfr[4];
            const int ph = ((kc * 4 + quad) ^ c7) * 8;
            #pragma unroll
            for (int mi = 0; mi < 4; mi++)
                af[mi] = *(const bf16x8*)&Xs[(wm * 64 + mi * 16 + lr) * 64 + ph];
            #pragma unroll
            for (int ni = 0; ni < 4; ni++)
                bfr[ni] = *(const bf16x8*)&Ws[(wn * 64 + ni * 16 + lr) * 64 + ph];
            if (z != 2) {   // swapped: acc[mi][ni] = (W.X^T) tile = D^T
                #pragma unroll
                for (int mi = 0; mi < 4; mi++)
                    #pragma unroll
                    for (int ni = 0; ni < 4; ni++)
                        acc[mi][ni] = __builtin_amdgcn_mfma_f32_16x16x32_bf16(
                            bfr[ni], af[mi], acc[mi][ni], 0, 0, 0);
            } else {
                #pragma unroll
                for (int mi = 0; mi < 4; mi++)
                    #pragma unroll
                    for (int ni = 0; ni < 4; ni++)
                        acc[mi][ni] = __builtin_amdgcn_mfma_f32_16x16x32_bf16(
                            af[mi], bfr[ni], acc[mi][ni], 0, 0, 0);
            }
        }
        __syncthreads();
    }

    if (z != 2) {
        // acc = D^T: col(lane&15) = s-row, reg r = d-direction.
        u16* dst = (z == 0) ? Qw : Kw;
        const float cs = (z == 0) ? 0.18033688011112042f : 1.0f;
        #pragma unroll
        for (int mi = 0; mi < 4; mi++) {
            const int sg = m0 + wm * 64 + mi * 16 + lr;
            const int b = sg >> 11, s = sg & 2047;
            #pragma unroll
            for (int ni = 0; ni < 4; ni++) {
                const int nb = n0 + wn * 64 + ni * 16 + quad * 4;
                const int h = nb >> 6, d0 = nb & 63;
                float4 bb4 = *(const float4*)&bias[nb];
                ushort4 vs;
                vs.x = f2b((acc[mi][ni][0] + bb4.x) * cs);
                vs.y = f2b((acc[mi][ni][1] + bb4.y) * cs);
                vs.z = f2b((acc[mi][ni][2] + bb4.z) * cs);
                vs.w = f2b((acc[mi][ni][3] + bb4.w) * cs);
                *(ushort4*)&dst[((size_t)(b * NHH + h) * SS + s) * HDD + d0] = vs;
            }
        }
    } else {
        // acc = D: col = d (n), reg r = s-direction -> V^T [b,h,d,s] stores.
        #pragma unroll
        for (int mi = 0; mi < 4; mi++)
            #pragma unroll
            for (int ni = 0; ni < 4; ni++) {
                const int mb = m0 + wm * 64 + mi * 16 + quad * 4;
                const int b = mb >> 11, s0 = mb & 2047;
                const int n = n0 + wn * 64 + ni * 16 + lr;
                const int h = n >> 6, d = n & 63;
                const float bv4 = bias[n];
                ushort4 vs;
                vs.x = f2b(acc[mi][ni][0] + bv4);
                vs.y = f2b(acc[mi][ni][1] + bv4);
                vs.z = f2b(acc[mi][ni][2] + bv4);
                vs.w = f2b(acc[mi][ni][3] + bv4);
                *(ushort4*)&Vw[((size_t)(b * NHH + h) * HDD + d) * SS + s0] = vs;
            }
    }
}

// ---------------------------------------------------------------------------
// attn: flash attention, M=0 softmax (p = exp2(s), Q pre-scaled), 512 threads
// = 8 waves, 128 q-rows/block. S^T score MFMA: each lane owns ONE q-row
// (q = lane&15) with 16 contiguous k values -> perm pair-pack + b64 P writes,
// scalar lsum. Double-buffered async K/V staging, pad-72 P slab.
// ---------------------------------------------------------------------------
__global__ __launch_bounds__(512) void attn(
    const u16* __restrict__ Qb, const u16* __restrict__ Kb,
    const u16* __restrict__ Vtb, float* __restrict__ Out)
{
    // hh = bid&63: all 16 q-blocks of a head land on XCD (hh&7).
    const int bid = blockIdx.x;
    const int hh = bid & 63, qt = bid >> 6;      // qt 0..15
    const int b = hh >> 4, h = hh & 15;
    const size_t hb = (size_t)hh * SS * HDD;

    __shared__ __align__(16) u16 Ks[2][64 * 64];
    __shared__ __align__(16) u16 Vs[2][64 * 64];
    __shared__ __align__(16) u16 Ps[8][16 * 72];   // [q][k], pad 72

    const int t = threadIdx.x;
    const int w = t >> 6, lane = t & 63, lr = lane & 15, quad = lane >> 4;
    const int l3 = lane >> 3, c7 = lane & 7;
    const int cl = (c7 ^ l3) * 8;          // swizzled source column (u16)

    // Q frags (lane map A==B: row = lane&15, k = quad*8+j), kept in VGPRs.
    bf16x8 qa[2];
    #pragma unroll
    for (int kc = 0; kc < 2; kc++)
        qa[kc] = *(const bf16x8*)&Qb[hb + (size_t)(qt * 128 + w * 16 + lr) * HDD
                                     + kc * 32 + quad * 8];

    // preload tile 0 into buffer 0: wave w stages rows w*8..w*8+7 of K and V^T
    {
        const int r8 = w * 8 + l3;
        gload16(&Kb [hb + (size_t)r8 * HDD + cl], &Ks[0][w * 8 * 64]);
        gload16(&Vtb[hb + (size_t)r8 * SS + cl],  &Vs[0][w * 8 * 64]);
    }
    __syncthreads();

    float lsum = 0.f;          // this lane's q-row (q = lr) partial sum
    f32x4 oc[4];
    #pragma unroll
    for (int ni = 0; ni < 4; ni++) oc[ni] = f32x4{0.f, 0.f, 0.f, 0.f};

    for (int kt = 0; kt < SS / 64; kt++) {
        const int bb = kt & 1;
        if (kt + 1 < SS / 64) {   // prefetch next tile into the other buffer
            const int r8 = w * 8 + l3;
            gload16(&Kb [hb + (size_t)((kt + 1) * 64 + r8) * HDD + cl],
                    &Ks[bb ^ 1][w * 8 * 64]);
            gload16(&Vtb[hb + (size_t)r8 * SS + (kt + 1) * 64 + cl],
                    &Vs[bb ^ 1][w * 8 * 64]);
        }

        // ---- S^T = K Q^T: D[m=k_row][n=q]; lane holds q=lr, k=ni*16+quad*4+r
        f32x4 sc4[4];
        #pragma unroll
        for (int ni = 0; ni < 4; ni++) sc4[ni] = f32x4{0.f, 0.f, 0.f, 0.f};
        #pragma unroll
        for (int kc = 0; kc < 2; kc++) {
            const int ph = ((kc * 4 + quad) ^ c7) * 8;
            #pragma unroll
            for (int ni = 0; ni < 4; ni++) {
                bf16x8 kf = *(const bf16x8*)&Ks[bb][(ni * 16 + lr) * 64 + ph];
                sc4[ni] = __builtin_amdgcn_mfma_f32_16x16x32_bf16(kf, qa[kc], sc4[ni], 0, 0, 0);
            }
        }

        // ---- p = exp2(s); scalar row-sum; pair-pack; 1 b64 write per ni.
        #pragma unroll
        for (int ni = 0; ni < 4; ni++) {
            float pv0 = __builtin_amdgcn_exp2f(sc4[ni][0]);
            float pv1 = __builtin_amdgcn_exp2f(sc4[ni][1]);
            float pv2 = __builtin_amdgcn_exp2f(sc4[ni][2]);
            float pv3 = __builtin_amdgcn_exp2f(sc4[ni][3]);
            lsum += (pv0 + pv1) + (pv2 + pv3);
            uint2 pk;
            pk.x = pk2b(pv0, pv1);
            pk.y = pk2b(pv2, pv3);
            *(uint2*)&Ps[w][lr * 72 + ni * 16 + quad * 4] = pk;
        }

        // ---- P: [q][k] A-frag read (row = lr, k = kc*32+quad*8)
        bf16x8 pa[2];
        #pragma unroll
        for (int kc = 0; kc < 2; kc++)
            pa[kc] = *(const bf16x8*)&Ps[w][lr * 72 + kc * 32 + quad * 8];

        // ---- O += P V
        #pragma unroll
        for (int kc = 0; kc < 2; kc++) {
            const int ph = ((kc * 4 + quad) ^ c7) * 8;
            #pragma unroll
            for (int ni = 0; ni < 4; ni++) {
                bf16x8 vf = *(const bf16x8*)&Vs[bb][(ni * 16 + lr) * 64 + ph];
                oc[ni] = __builtin_amdgcn_mfma_f32_16x16x32_bf16(pa[kc], vf, oc[ni], 0, 0, 0);
            }
        }
        __syncthreads();   // reads of buf bb done; prefetch into bb^1 landed
    }

    // ---- finalize l: sum the 4 quads holding the same q (lanes lr, lr+16, ..)
    lsum += __shfl_xor(lsum, 16);
    lsum += __shfl_xor(lsum, 32);
    const float linv = 1.0f / lsum;

    // oc rows are q = quad*4+r; fetch inv from lane (quad*4+r) (quad 0 set).
    #pragma unroll
    for (int ni = 0; ni < 4; ni++)
        #pragma unroll
        for (int r = 0; r < 4; r++) {
            const float inv = __shfl(linv, quad * 4 + r);
            const int rq = qt * 128 + w * 16 + quad * 4 + r;
            Out[((size_t)(b * SS + rq)) * HH + h * HDD + ni * 16 + lr] =
                oc[ni][r] * inv;
        }
}

// ---------------------------------------------------------------------------
extern "C" void kernel_launch(void* const* d_in, const int* in_sizes, int n_in,
                              void* d_out, int out_size, void* d_ws, size_t ws_size,
                              hipStream_t stream) {
    const float* X  = (const float*)d_in[0];
    const float* Wq = (const float*)d_in[1];
    const float* bq = (const float*)d_in[2];
    const float* Wk = (const float*)d_in[3];
    const float* bk = (const float*)d_in[4];
    const float* Wv = (const float*)d_in[5];
    const float* bv = (const float*)d_in[6];
    float* Out = (float*)d_out;

    const size_t elems = (size_t)BB * SS * HH;  // 8,388,608
    u16* Qw = (u16*)d_ws;                        // Q (pre-scaled) [b,h,s,d]
    u16* Kw = Qw + elems;                        // K [b,h,s,d]
    u16* Vw = Kw + elems;                        // V^T [b,h,d,s]
    // Xb/Wt scratch in d_out (23.1 MB < 33.5 MB; attn fully overwrites).
    u16* Xb = (u16*)d_out;
    u16* Wt = Xb + elems;

    conv<<<dim3(4096 + 3072), 256, 0, stream>>>(X, Wq, Wk, Wv, Xb, Wt);
    qkv_gemm<<<dim3(64, 8, 3), 256, 0, stream>>>(Xb, Wt, bq, bk, bv, Qw, Kw, Vw);
    attn<<<dim3(1024), 512, 0, stream>>>(Qw, Kw, Vw, Out);
}